// Round 3
// baseline (653.362 us; speedup 1.0000x reference)
//
#include <hip/hip_runtime.h>
#include <math.h>

#define PI_F 3.14159265358979323846f
// Wave-level LDS sync (k_col only): DS ops from one wave execute in order; waitcnt drains
// them, "memory" clobber stops compiler reordering. No s_barrier for wave-private data.
#define WSYNC() asm volatile("s_waitcnt lgkmcnt(0)" ::: "memory")

// ---------------- complex helpers ----------------
__device__ __forceinline__ float2 cmul(float2 a, float2 b) {      // a*b
    return make_float2(a.x * b.x - a.y * b.y, a.x * b.y + a.y * b.x);
}
__device__ __forceinline__ float2 cmulc(float2 a, float2 b) {     // a*conj(b)
    return make_float2(a.x * b.x + a.y * b.y, a.y * b.x - a.x * b.y);
}
__device__ __forceinline__ int digitrev4(int p) {                 // reverse 4 base-4 digits
    return ((p & 3) << 6) | (((p >> 2) & 3) << 4) | (((p >> 4) & 3) << 2) | ((p >> 6) & 3);
}
__device__ __forceinline__ int bitrev8(int p) {                   // reverse 8 bits
    return (int)(__brev((unsigned int)p) >> 24);
}
// XOR bank-swizzle within a 256-point line (k_col): logical elem e lives at e ^ ((e>>4)&15).
// Involution; every radix-4 stage's b64 pattern = exactly 4 lanes/bank-pair (wave64 minimum).
__device__ __forceinline__ int SW(int i) { return i ^ ((i >> 4) & 15); }

// W_256^eu, ^2eu, ^3eu via one sincos + angle addition (k_col radix-4 path)
__device__ __forceinline__ void tw3(int eu, float2& w1, float2& w2, float2& w3) {
    float sn, cs;
    __sincosf(-(2.0f * PI_F / 256.0f) * (float)eu, &sn, &cs);
    w1 = make_float2(cs, sn);
    w2 = cmul(w1, w1);
    w3 = cmul(w2, w1);
}

// ---------------- radix-4 butterfly cores (twiddle-free) ----------------
__device__ __forceinline__ void bfly4_fwd(float2 a0, float2 a1, float2 a2, float2 a3,
                                          float2& o0, float2& o1, float2& o2, float2& o3) {
    float2 t0 = make_float2(a0.x + a2.x, a0.y + a2.y);
    float2 t1 = make_float2(a0.x - a2.x, a0.y - a2.y);
    float2 t2 = make_float2(a1.x + a3.x, a1.y + a3.y);
    float2 u  = make_float2(a1.x - a3.x, a1.y - a3.y);
    float2 t3 = make_float2(u.y, -u.x);                 // -i*u
    o0 = make_float2(t0.x + t2.x, t0.y + t2.y);
    o1 = make_float2(t1.x + t3.x, t1.y + t3.y);
    o2 = make_float2(t0.x - t2.x, t0.y - t2.y);
    o3 = make_float2(t1.x - t3.x, t1.y - t3.y);
}
__device__ __forceinline__ void bfly4_inv(float2 a0, float2 a1, float2 a2, float2 a3,
                                          float2& o0, float2& o1, float2& o2, float2& o3) {
    float2 t0 = make_float2(a0.x + a2.x, a0.y + a2.y);
    float2 t1 = make_float2(a0.x - a2.x, a0.y - a2.y);
    float2 t2 = make_float2(a1.x + a3.x, a1.y + a3.y);
    float2 u  = make_float2(a1.x - a3.x, a1.y - a3.y);
    float2 t3 = make_float2(-u.y, u.x);                 // +i*u
    o0 = make_float2(t0.x + t2.x, t0.y + t2.y);
    o1 = make_float2(t1.x + t3.x, t1.y + t3.y);
    o2 = make_float2(t0.x - t2.x, t0.y - t2.y);
    o3 = make_float2(t1.x - t3.x, t1.y - t3.y);
}

// ---------------- radix-4 stages on a swizzled 256-line in LDS (k_col) ----------------
template<int S>
__device__ __forceinline__ void stage_fwd_j(float2* line, int j, float2 w1, float2 w2, float2 w3) {
    const int h = 1 << (2 * S);
    int k  = j & (h - 1);
    int i0 = ((j >> (2 * S)) << (2 * S + 2)) + k;
    int p0 = SW(i0), p1 = SW(i0 + h), p2 = SW(i0 + 2 * h), p3 = SW(i0 + 3 * h);
    float2 a0 = line[p0], a1 = line[p1], a2 = line[p2], a3 = line[p3];
    float2 o0, o1, o2, o3;
    bfly4_fwd(a0, a1, a2, a3, o0, o1, o2, o3);
    line[p0] = o0;
    line[p1] = cmul(o1, w1);
    line[p2] = cmul(o2, w2);
    line[p3] = cmul(o3, w3);
}
template<int S>
__device__ __forceinline__ void stage_inv_j(float2* line, int j, float2 w1, float2 w2, float2 w3) {
    const int h = 1 << (2 * S);
    int k  = j & (h - 1);
    int i0 = ((j >> (2 * S)) << (2 * S + 2)) + k;
    int p0 = SW(i0), p1 = SW(i0 + h), p2 = SW(i0 + 2 * h), p3 = SW(i0 + 3 * h);
    float2 b0 = line[p0];
    float2 b1 = cmulc(line[p1], w1);
    float2 b2 = cmulc(line[p2], w2);
    float2 b3 = cmulc(line[p3], w3);
    float2 o0, o1, o2, o3;
    bfly4_inv(b0, b1, b2, b3, o0, o1, o2, o3);
    line[p0] = o0; line[p1] = o1; line[p2] = o2; line[p3] = o3;
}

// ---------------- register FFT along W: radix-2 shfl_xor stages, zero LDS ----------------
// Layout: lane L holds elements 4L..4L+3 of a 256-line (2 lines a[],b[] per wave).
// Forward DIF, stages h=128..4 are cross-lane (mask = h/4), h=2,1 lane-local.
// Output position p holds frequency bitrev8(p). Sum-lanes use exact (1,0) twiddle.
template<int MB>
__device__ __forceinline__ void xs_fwd(float2* a, float2* b, int lane,
                                       float step, float cC, float sC) {
    float dm = (lane & MB) ? 1.0f : 0.0f;               // 1 on diff lanes
    float s  = 1.0f - 2.0f * dm;                        // +1 sum, -1 diff
    float ang = step * dm * (float)(lane & (MB - 1));   // tw0 angle (0 on sum lanes)
    float sn, cs; __sincosf(ang, &sn, &cs);
    float2 tw = make_float2(cs, sn);                    // (1,0) exactly on sum lanes
    float2 Cm = make_float2(1.0f + dm * (cC - 1.0f), dm * sC);  // per-slot rotation, 1 on sum
#pragma unroll
    for (int d = 0; d < 4; ++d) {
        float tax = __shfl_xor(a[d].x, MB), tay = __shfl_xor(a[d].y, MB);
        float tbx = __shfl_xor(b[d].x, MB), tby = __shfl_xor(b[d].y, MB);
        float2 ra = make_float2(tax + s * a[d].x, tay + s * a[d].y);
        float2 rb = make_float2(tbx + s * b[d].x, tby + s * b[d].y);
        a[d] = cmul(ra, tw);
        b[d] = cmul(rb, tw);
        tw = cmul(tw, Cm);
    }
}
// Inverse DIT: pre-multiply diff lane's value by conj twiddle (positive angles), exchange, add/sub.
template<int MB>
__device__ __forceinline__ void xs_inv(float2* a, float2* b, int lane,
                                       float step, float cC, float sC) {
    float dm = (lane & MB) ? 1.0f : 0.0f;
    float s  = 1.0f - 2.0f * dm;
    float ang = step * dm * (float)(lane & (MB - 1));   // positive = conj of fwd
    float sn, cs; __sincosf(ang, &sn, &cs);
    float2 tw = make_float2(cs, sn);
    float2 Cm = make_float2(1.0f + dm * (cC - 1.0f), dm * sC);
#pragma unroll
    for (int d = 0; d < 4; ++d) {
        float2 pa = cmul(a[d], tw);                     // own' (unchanged on sum lanes)
        float2 pb = cmul(b[d], tw);
        float tax = __shfl_xor(pa.x, MB), tay = __shfl_xor(pa.y, MB);
        float tbx = __shfl_xor(pb.x, MB), tby = __shfl_xor(pb.y, MB);
        a[d] = make_float2(tax + s * pa.x, tay + s * pa.y);
        b[d] = make_float2(tbx + s * pb.x, tby + s * pb.y);
        tw = cmul(tw, Cm);
    }
}
// Lane-local tail: fwd h=2 then h=1 (radix-2 positions, bitrev-consistent)
__device__ __forceinline__ void local_fwd(float2* v) {
    float2 u0 = make_float2(v[0].x + v[2].x, v[0].y + v[2].y);
    float2 u2 = make_float2(v[0].x - v[2].x, v[0].y - v[2].y);
    float2 u1 = make_float2(v[1].x + v[3].x, v[1].y + v[3].y);
    float2 w  = make_float2(v[1].x - v[3].x, v[1].y - v[3].y);
    float2 u3 = make_float2(w.y, -w.x);                 // -i*w  (W_256^64 on h=2 diff)
    v[0] = make_float2(u0.x + u1.x, u0.y + u1.y);
    v[1] = make_float2(u0.x - u1.x, u0.y - u1.y);
    v[2] = make_float2(u2.x + u3.x, u2.y + u3.y);
    v[3] = make_float2(u2.x - u3.x, u2.y - u3.y);
}
// Lane-local head of inverse: h=1 then h=2 (conj: +i)
__device__ __forceinline__ void local_inv(float2* v) {
    float2 u0 = make_float2(v[0].x + v[1].x, v[0].y + v[1].y);
    float2 u1 = make_float2(v[0].x - v[1].x, v[0].y - v[1].y);
    float2 u2 = make_float2(v[2].x + v[3].x, v[2].y + v[3].y);
    float2 u3 = make_float2(v[2].x - v[3].x, v[2].y - v[3].y);
    float2 w  = make_float2(-u3.y, u3.x);               // +i*u3
    v[0] = make_float2(u0.x + u2.x, u0.y + u2.y);
    v[2] = make_float2(u0.x - u2.x, u0.y - u2.y);
    v[1] = make_float2(u1.x + w.x, u1.y + w.y);
    v[3] = make_float2(u1.x - w.x, u1.y - w.y);
}

// gain of the (fftshift-space) reference at centered freq (fy, fx)
__device__ __forceinline__ float gain1(float fy, float fx, const float* sw) {
    float r2 = fy * fy + fx * fx;
    float theta = atan2f(fy, fx) + PI_F;
    int idx = ((int)floorf(theta * (4.0f / PI_F))) & 7;
    float wv = sw[idx];
    return (r2 > 1474.56f) ? wv : 1.0f;                 // r > 0.3*128, r^2 integer
}

// ---------------- gain LUT: lut2[w_stored][h_stored]. W order = bitrev8 (radix-2 rows),
// H order = digitrev4 (radix-4 columns). ----------------
__global__ __launch_bounds__(256) void k_gain_lut(const float* __restrict__ wts, float* __restrict__ lut2) {
    __shared__ float sw[8];
    int h = threadIdx.x, w = blockIdx.x;
    if (h < 8) sw[h] = wts[h];
    __syncthreads();
    int kw = bitrev8(w), kh = digitrev4(h);
    float fx  = (kw < 128) ? (float)kw : (float)(kw - 256);
    float fx2 = (kw == 128) ? -128.0f : -fx;
    float fy  = (kh < 128) ? (float)kh : (float)(kh - 256);
    float fy2 = (kh == 128) ? -128.0f : -fy;
    float g1 = gain1(fy, fx, sw);
    float g2 = gain1(fy2, fx2, sw);                     // symmetrize -> real filter
    lut2[w * 256 + h] = (1.0f + 0.5f * (g1 + g2)) * (1.0f / 65536.0f);
}

// ---------------- Pass 1: forward FFT along W, fully in registers. Wave owns 2 rows. ----------------
__global__ __launch_bounds__(256) void k_row_fwd(const float* __restrict__ x, float* __restrict__ out) {
    int t = threadIdx.x, wv = t >> 6, lane = t & 63;
    int gr = blockIdx.x * 8 + wv * 2;                   // global row id (pair-aligned, same image)
    int q = gr >> 8, h = gr & 255;
    int plane = ((q >> 7) << 8) + ((q & 127) << 1);
    size_t rA = ((size_t)plane << 16) + ((size_t)h << 8);
    size_t rB = rA + 65536;
    int w4 = lane * 4;
    float4 re0 = *(const float4*)(x + rA + w4);
    float4 im0 = *(const float4*)(x + rB + w4);
    float4 re1 = *(const float4*)(x + rA + 256 + w4);
    float4 im1 = *(const float4*)(x + rB + 256 + w4);
    float2 a[4], b[4];
    a[0] = make_float2(re0.x, im0.x); a[1] = make_float2(re0.y, im0.y);
    a[2] = make_float2(re0.z, im0.z); a[3] = make_float2(re0.w, im0.w);
    b[0] = make_float2(re1.x, im1.x); b[1] = make_float2(re1.y, im1.y);
    b[2] = make_float2(re1.z, im1.z); b[3] = make_float2(re1.w, im1.w);
    // cross-lane stages h=128..4 (mask 32..1); angles: tw0 = -pi*(L&(MB-1))/MB, C = W_256^{32/MB}
    xs_fwd<32>(a, b, lane, -0.09817477f, 0.99969882f, -0.02454123f);
    xs_fwd<16>(a, b, lane, -0.19634954f, 0.99879546f, -0.04906767f);
    xs_fwd< 8>(a, b, lane, -0.39269908f, 0.99518473f, -0.09801714f);
    xs_fwd< 4>(a, b, lane, -0.78539816f, 0.98078528f, -0.19509032f);
    xs_fwd< 2>(a, b, lane, -1.57079633f, 0.92387953f, -0.38268343f);
    xs_fwd< 1>(a, b, lane, -3.14159265f, 0.70710678f, -0.70710678f);
    local_fwd(a); local_fwd(b);
    *(float4*)(out + rA + w4)       = make_float4(a[0].x, a[1].x, a[2].x, a[3].x);
    *(float4*)(out + rB + w4)       = make_float4(a[0].y, a[1].y, a[2].y, a[3].y);
    *(float4*)(out + rA + 256 + w4) = make_float4(b[0].x, b[1].x, b[2].x, b[3].x);
    *(float4*)(out + rB + 256 + w4) = make_float4(b[0].y, b[1].y, b[2].y, b[3].y);
}

// ---------------- Pass 2: col FFT + gain + col IFFT (radix-4 in swizzled LDS). ----------------
template<bool USE_LUT>
__global__ __launch_bounds__(256) void k_col(float* __restrict__ data,
                                             const float* __restrict__ lut2,
                                             const float* __restrict__ wts) {
    __shared__ float2 tile[16][256];                    // 32 KiB exactly -> 5 blocks/CU
    int t = threadIdx.x;
    int q = blockIdx.x >> 4, wt = blockIdx.x & 15, w0 = wt * 16;
    int plane = ((q >> 7) << 8) + ((q & 127) << 1);
    size_t baseA = ((size_t)plane << 16) + (size_t)w0;
    size_t baseB = baseA + 65536;
    int c0 = (t & 3) * 4, h0 = (t >> 2) * 4;
    int wv = t >> 6, lane = t & 63;
    int i0 = lane * 4;

    // -------- fallback gains (no workspace): stash wts in tile scratch, compute to regs --------
    float4 gAr[2], gBr[2];
    if (!USE_LUT) {
        if (t < 8) ((float*)tile)[t] = wts[t];
        __syncthreads();
        const float* swp = (const float*)tile;
#pragma unroll
        for (int cp = 0; cp < 2; ++cp) {
#pragma unroll
            for (int cc = 0; cc < 2; ++cc) {
                int col = wv * 4 + cp * 2 + cc;
                int kw = bitrev8(w0 + col);             // rows are radix-2 -> bitrev W order
                float fx  = (kw < 128) ? (float)kw : (float)(kw - 256);
                float fx2 = (kw == 128) ? -128.0f : -fx;
                float4 g;
#pragma unroll
                for (int d = 0; d < 4; ++d) {
                    int kh = digitrev4(i0 + d);
                    float fy  = (kh < 128) ? (float)kh : (float)(kh - 256);
                    float fy2 = (kh == 128) ? -128.0f : -fy;
                    float g1v = gain1(fy, fx, swp);
                    float g2v = gain1(fy2, fx2, swp);
                    (&g.x)[d] = (1.0f + 0.5f * (g1v + g2v)) * (1.0f / 65536.0f);
                }
                if (cc == 0) gAr[cp] = g; else gBr[cp] = g;
            }
        }
        __syncthreads();
    }

    // -------- staging in: thread -> cols c0..c0+3, rows h0..h0+3 (b64 LDS writes, swizzled) --------
    {
        float4 reR[4], imR[4];
#pragma unroll
        for (int r = 0; r < 4; ++r) {
            reR[r] = *(const float4*)(data + baseA + (size_t)(h0 + r) * 256 + c0);
            imR[r] = *(const float4*)(data + baseB + (size_t)(h0 + r) * 256 + c0);
        }
#pragma unroll
        for (int r = 0; r < 4; ++r) {
            int p = SW(h0 + r);
#pragma unroll
            for (int k = 0; k < 4; ++k)
                tile[c0 + k][p] = make_float2((&reR[r].x)[k], (&imR[r].x)[k]);
        }
    }
    __syncthreads();

    // -------- wave-private column FFTs: lane = butterfly j, two lines interleaved per sync --------
    float2 w31, w32, w33, w21, w22, w23, w11, w12, w13;
    tw3(lane,             w31, w32, w33);
    tw3((lane & 15) << 2, w21, w22, w23);
    tw3((lane & 3)  << 4, w11, w12, w13);
    int p0 = SW(i0), p1 = SW(i0 + 1), p2 = SW(i0 + 2), p3 = SW(i0 + 3);
#pragma unroll
    for (int cp = 0; cp < 2; ++cp) {
        int colA = wv * 4 + cp * 2, colB = colA + 1;
        float2* LA = tile[colA];
        float2* LB = tile[colB];
        float4 gA, gB;
        if (USE_LUT) {
            gA = *(const float4*)(lut2 + (size_t)(w0 + colA) * 256 + i0);
            gB = *(const float4*)(lut2 + (size_t)(w0 + colB) * 256 + i0);
        } else {
            gA = gAr[cp]; gB = gBr[cp];
        }
        stage_fwd_j<3>(LA, lane, w31, w32, w33); stage_fwd_j<3>(LB, lane, w31, w32, w33); WSYNC();
        stage_fwd_j<2>(LA, lane, w21, w22, w23); stage_fwd_j<2>(LB, lane, w21, w22, w23); WSYNC();
        stage_fwd_j<1>(LA, lane, w11, w12, w13); stage_fwd_j<1>(LB, lane, w11, w12, w13); WSYNC();
        // fused fwd0 + gain + inv0 (stage-0 butterfly j covers logical elems 4j..4j+3 = LUT order)
        {
            float2 o0, o1, o2, o3, r0, r1, r2, r3;
            bfly4_fwd(LA[p0], LA[p1], LA[p2], LA[p3], o0, o1, o2, o3);
            o0.x *= gA.x; o0.y *= gA.x; o1.x *= gA.y; o1.y *= gA.y;
            o2.x *= gA.z; o2.y *= gA.z; o3.x *= gA.w; o3.y *= gA.w;
            bfly4_inv(o0, o1, o2, o3, r0, r1, r2, r3);
            LA[p0] = r0; LA[p1] = r1; LA[p2] = r2; LA[p3] = r3;
            bfly4_fwd(LB[p0], LB[p1], LB[p2], LB[p3], o0, o1, o2, o3);
            o0.x *= gB.x; o0.y *= gB.x; o1.x *= gB.y; o1.y *= gB.y;
            o2.x *= gB.z; o2.y *= gB.z; o3.x *= gB.w; o3.y *= gB.w;
            bfly4_inv(o0, o1, o2, o3, r0, r1, r2, r3);
            LB[p0] = r0; LB[p1] = r1; LB[p2] = r2; LB[p3] = r3;
        }
        WSYNC();
        stage_inv_j<1>(LA, lane, w11, w12, w13); stage_inv_j<1>(LB, lane, w11, w12, w13); WSYNC();
        stage_inv_j<2>(LA, lane, w21, w22, w23); stage_inv_j<2>(LB, lane, w21, w22, w23); WSYNC();
        stage_inv_j<3>(LA, lane, w31, w32, w33); stage_inv_j<3>(LB, lane, w31, w32, w33); WSYNC();
    }
    __syncthreads();

    // -------- staging out (mirror of staging in) --------
    {
#pragma unroll
        for (int r = 0; r < 4; ++r) {
            int p = SW(h0 + r);
            float2 v0 = tile[c0 + 0][p], v1 = tile[c0 + 1][p];
            float2 v2 = tile[c0 + 2][p], v3 = tile[c0 + 3][p];
            *(float4*)(data + baseA + (size_t)(h0 + r) * 256 + c0) = make_float4(v0.x, v1.x, v2.x, v3.x);
            *(float4*)(data + baseB + (size_t)(h0 + r) * 256 + c0) = make_float4(v0.y, v1.y, v2.y, v3.y);
        }
    }
}

// ---------------- Pass 3: inverse FFT along W, fully in registers. Wave owns 2 rows. ----------------
__global__ __launch_bounds__(256) void k_row_inv(float* __restrict__ data) {
    int t = threadIdx.x, wv = t >> 6, lane = t & 63;
    int gr = blockIdx.x * 8 + wv * 2;
    int q = gr >> 8, h = gr & 255;
    int plane = ((q >> 7) << 8) + ((q & 127) << 1);
    size_t rA = ((size_t)plane << 16) + ((size_t)h << 8);
    size_t rB = rA + 65536;
    int w4 = lane * 4;
    float4 re0 = *(const float4*)(data + rA + w4);
    float4 im0 = *(const float4*)(data + rB + w4);
    float4 re1 = *(const float4*)(data + rA + 256 + w4);
    float4 im1 = *(const float4*)(data + rB + 256 + w4);
    float2 a[4], b[4];
    a[0] = make_float2(re0.x, im0.x); a[1] = make_float2(re0.y, im0.y);
    a[2] = make_float2(re0.z, im0.z); a[3] = make_float2(re0.w, im0.w);
    b[0] = make_float2(re1.x, im1.x); b[1] = make_float2(re1.y, im1.y);
    b[2] = make_float2(re1.z, im1.z); b[3] = make_float2(re1.w, im1.w);
    local_inv(a); local_inv(b);
    // cross-lane inverse stages h=4..128 (mask 1..32), conj twiddles (positive angles)
    xs_inv< 1>(a, b, lane,  3.14159265f, 0.70710678f,  0.70710678f);
    xs_inv< 2>(a, b, lane,  1.57079633f, 0.92387953f,  0.38268343f);
    xs_inv< 4>(a, b, lane,  0.78539816f, 0.98078528f,  0.19509032f);
    xs_inv< 8>(a, b, lane,  0.39269908f, 0.99518473f,  0.09801714f);
    xs_inv<16>(a, b, lane,  0.19634954f, 0.99879546f,  0.04906767f);
    xs_inv<32>(a, b, lane,  0.09817477f, 0.99969882f,  0.02454123f);
    *(float4*)(data + rA + w4)       = make_float4(a[0].x, a[1].x, a[2].x, a[3].x);   // re -> ch 2c
    *(float4*)(data + rB + w4)       = make_float4(a[0].y, a[1].y, a[2].y, a[3].y);   // im -> ch 2c+1
    *(float4*)(data + rA + 256 + w4) = make_float4(b[0].x, b[1].x, b[2].x, b[3].x);
    *(float4*)(data + rB + 256 + w4) = make_float4(b[0].y, b[1].y, b[2].y, b[3].y);
}

extern "C" void kernel_launch(void* const* d_in, const int* in_sizes, int n_in,
                              void* d_out, int out_size, void* d_ws, size_t ws_size,
                              hipStream_t stream) {
    const float* x   = (const float*)d_in[0];
    const float* wts = (const float*)d_in[1];
    float* out = (float*)d_out;
    (void)in_sizes; (void)n_in; (void)out_size;
    bool use_lut = (ws_size >= 256 * 256 * sizeof(float)) && (d_ws != nullptr);
    if (use_lut) {
        k_gain_lut<<<256, 256, 0, stream>>>(wts, (float*)d_ws);
    }
    // 512 image-pairs (B=4, C=256 paired), H=W=256; 131072 rows total, 8 per block
    k_row_fwd<<<16384, 256, 0, stream>>>(x, out);
    if (use_lut) {
        k_col<true><<<8192, 256, 0, stream>>>(out, (const float*)d_ws, wts);
    } else {
        k_col<false><<<8192, 256, 0, stream>>>(out, nullptr, wts);
    }
    k_row_inv<<<16384, 256, 0, stream>>>(out);
}